// Round 1
// baseline (565.773 us; speedup 1.0000x reference)
//
#include <hip/hip_runtime.h>
#include <cstddef>

// Problem constants
#define BATCH 8
#define NN 1024
#define IN_DIM 768
#define OUT_DIM 96
#define HEADS 8
#define HO 768              // HEADS*OUT_DIM
#define M_ROWS 8192         // BATCH*NN
#define NCOLS 1536          // HO (h) + 768 (gate logits)

// Workspace layout (in floats)
#define WS_BCAT   0
#define WS_H      (WS_BCAT + IN_DIM*NCOLS)           // 1,179,648
#define WS_GLOG   (WS_H + 64*NN*OUT_DIM)             // + 6,291,456
#define WS_ASRC   (WS_GLOG + M_ROWS*768)             // + 6,291,456
#define WS_ADST   (WS_ASRC + 64*NN)
#define WS_FO     (WS_ADST + 64*NN)

// ---------------- pack kernels ----------------
// Bcat[i][c] for c<768: W[c/96][i][c%96]; for c>=768: Hw[c-768][i]
__global__ void pack_w_kernel(const float* __restrict__ W, float* __restrict__ Bcat) {
    int idx = blockIdx.x * 256 + threadIdx.x;   // 589824 total
    if (idx >= IN_DIM * 768) return;
    int i = idx / 768, c = idx % 768;
    int h = c / OUT_DIM, o = c % OUT_DIM;
    Bcat[(size_t)i * NCOLS + c] = W[(size_t)h * IN_DIM * OUT_DIM + (size_t)i * OUT_DIM + o];
}

__global__ void pack_hw_kernel(const float* __restrict__ Hw, float* __restrict__ Bcat) {
    __shared__ float ts[32][33];
    int k0 = blockIdx.x * 32, i0 = blockIdx.y * 32;
    int tx = threadIdx.x % 32, ty = threadIdx.x / 32;  // ty 0..7
    for (int p = 0; p < 4; ++p) {
        int r = p * 8 + ty;
        ts[tx][r] = Hw[(size_t)(k0 + r) * IN_DIM + i0 + tx];  // ts[x][y] = Hw[k0+y][i0+x]
    }
    __syncthreads();
    for (int p = 0; p < 4; ++p) {
        int r = p * 8 + ty;
        // Bcat[i0+r][768 + k0+tx] = Hw[k0+tx][i0+r] = ts[r][tx]
        Bcat[(size_t)(i0 + r) * NCOLS + 768 + k0 + tx] = ts[r][tx];
    }
}

// ---------------- GEMM1: X[8192,768] @ Bcat[768,1536] ----------------
// 128x128 tile, 8x8 microtile per thread, fp32.
__global__ __launch_bounds__(256) void gemm1_kernel(
        const float* __restrict__ A, const float* __restrict__ Bc,
        float* __restrict__ h_ws, float* __restrict__ glog) {
    __shared__ __align__(16) float As[16][132];
    __shared__ __align__(16) float Bs[16][132];
    int m0 = blockIdx.x * 128;
    int c0 = blockIdx.y * 128;
    int t = threadIdx.x;
    int tx = t % 16, ty = t / 16;
    float acc[8][8] = {};
    for (int k0 = 0; k0 < IN_DIM; k0 += 16) {
        for (int q = 0; q < 2; ++q) {
            int f = t + q * 256;                    // 0..511
            int r = f >> 2, kk = (f & 3) * 4;       // A tile: 128 rows x 16 k
            float4 av = *(const float4*)(A + (size_t)(m0 + r) * IN_DIM + k0 + kk);
            As[kk + 0][r] = av.x; As[kk + 1][r] = av.y;
            As[kk + 2][r] = av.z; As[kk + 3][r] = av.w;
            int kb = f >> 5, c4 = (f & 31) * 4;     // B tile: 16 k x 128 cols
            *(float4*)(&Bs[kb][c4]) = *(const float4*)(Bc + (size_t)(k0 + kb) * NCOLS + c0 + c4);
        }
        __syncthreads();
        for (int k = 0; k < 16; ++k) {
            float4 a0 = *(const float4*)(&As[k][ty * 4]);
            float4 a1 = *(const float4*)(&As[k][64 + ty * 4]);
            float4 b0 = *(const float4*)(&Bs[k][tx * 4]);
            float4 b1 = *(const float4*)(&Bs[k][64 + tx * 4]);
            float ar[8] = {a0.x, a0.y, a0.z, a0.w, a1.x, a1.y, a1.z, a1.w};
            float br[8] = {b0.x, b0.y, b0.z, b0.w, b1.x, b1.y, b1.z, b1.w};
            #pragma unroll
            for (int i = 0; i < 8; ++i)
                #pragma unroll
                for (int j = 0; j < 8; ++j)
                    acc[i][j] += ar[i] * br[j];
        }
        __syncthreads();
    }
    #pragma unroll
    for (int i = 0; i < 8; ++i) {
        int m = m0 + ((i < 4) ? (ty * 4 + i) : (64 + ty * 4 + (i - 4)));
        int b = m >> 10, n = m & 1023;
        #pragma unroll
        for (int jh = 0; jh < 2; ++jh) {
            int c = c0 + ((jh == 0) ? (tx * 4) : (64 + tx * 4));
            float4 v = make_float4(acc[i][jh * 4 + 0], acc[i][jh * 4 + 1],
                                   acc[i][jh * 4 + 2], acc[i][jh * 4 + 3]);
            if (c < 768) {
                int hh = c / OUT_DIM, o = c % OUT_DIM;   // 4-aligned group never crosses 96
                *(float4*)(h_ws + ((size_t)(b * 8 + hh) * NN + n) * OUT_DIM + o) = v;
            } else {
                *(float4*)(glog + (size_t)m * 768 + (c - 768)) = v;
            }
        }
    }
}

// ---------------- a_src/a_dst: one wave per (b,h,n) row ----------------
__global__ void a_kernel(const float* __restrict__ h_ws,
                         const float* __restrict__ w_src, const float* __restrict__ w_dst,
                         float* __restrict__ a_src, float* __restrict__ a_dst) {
    int wid = threadIdx.x >> 6;
    int lane = threadIdx.x & 63;
    int row = blockIdx.x * 4 + wid;        // 0..65535  (= bh*1024 + n)
    int head = (row >> 10) & 7;
    const float* hp = h_ws + (size_t)row * OUT_DIM;
    float t0 = tanhf(hp[lane]);
    float ps = t0 * w_src[head * OUT_DIM + lane];
    float pd = t0 * w_dst[head * OUT_DIM + lane];
    if (lane < 32) {
        float t1 = tanhf(hp[64 + lane]);
        ps += t1 * w_src[head * OUT_DIM + 64 + lane];
        pd += t1 * w_dst[head * OUT_DIM + 64 + lane];
    }
    #pragma unroll
    for (int m = 32; m >= 1; m >>= 1) {
        ps += __shfl_xor(ps, m);
        pd += __shfl_xor(pd, m);
    }
    if (lane == 0) { a_src[row] = ps; a_dst[row] = pd; }
}

// ---------------- attention: per (b,h, i-tile of 128): softmax-weighted sum ----------------
// No max-subtraction needed: |scores| <= ~16, exp fine in fp32; masked -> e=0.
__global__ __launch_bounds__(256) void attn_kernel(
        const float* __restrict__ h_ws, const float* __restrict__ adj,
        const float* __restrict__ a_src_g, const float* __restrict__ a_dst_g,
        float* __restrict__ fo_ws) {
    __shared__ __align__(16) float a_dst_s[1024];
    __shared__ __align__(16) float a_src_s[128];
    __shared__ __align__(16) float h_s[64 * 96];
    __shared__ __align__(16) float e_s[64 * 132];
    int blk = blockIdx.x;
    int bh = blk >> 3;          // 0..63
    int i0 = (blk & 7) * 128;
    int b = bh >> 3;
    int t = threadIdx.x;
    const float* hhead = h_ws + (size_t)bh * NN * OUT_DIM;
    for (int q = 0; q < 4; ++q) a_dst_s[q * 256 + t] = a_dst_g[bh * 1024 + q * 256 + t];
    if (t < 128) a_src_s[t] = a_src_g[bh * 1024 + i0 + t];
    __syncthreads();
    int tx = t % 16, ty = t / 16;
    float acc[8][6] = {};
    float dsum[8] = {};
    const float* adj_b = adj + (size_t)b * NN * NN;
    int il = t >> 1, jhalf = (t & 1) * 32;
    float si = a_src_s[il];
    for (int j0 = 0; j0 < 1024; j0 += 64) {
        // stage h tile (64 x 96), contiguous = conflict-free
        for (int q = 0; q < 6; ++q) {
            int f = t + q * 256;
            *(float4*)(h_s + f * 4) = *(const float4*)(hhead + (size_t)j0 * OUT_DIM + f * 4);
        }
        // scores -> e_s[j][i] (pad 132; writes max 2-way)
        for (int w4 = 0; w4 < 8; ++w4) {
            float4 av = *(const float4*)(adj_b + (size_t)(i0 + il) * NN + j0 + jhalf + w4 * 4);
            float aa[4] = {av.x, av.y, av.z, av.w};
            #pragma unroll
            for (int u = 0; u < 4; ++u) {
                int jl = jhalf + w4 * 4 + u;
                float s = si + a_dst_s[j0 + jl];
                s = (s >= 0.f) ? s : 0.2f * s;
                float e = (aa[u] != 0.f) ? __expf(s) : 0.f;
                e_s[jl * 132 + il] = e;
            }
        }
        __syncthreads();
        for (int j = 0; j < 64; ++j) {
            float4 e0 = *(const float4*)(e_s + j * 132 + ty * 8);
            float4 e1 = *(const float4*)(e_s + j * 132 + ty * 8 + 4);
            float2 h0 = *(const float2*)(h_s + j * 96 + tx * 6);
            float2 h1 = *(const float2*)(h_s + j * 96 + tx * 6 + 2);
            float2 h2 = *(const float2*)(h_s + j * 96 + tx * 6 + 4);
            float er[8] = {e0.x, e0.y, e0.z, e0.w, e1.x, e1.y, e1.z, e1.w};
            float hr[6] = {h0.x, h0.y, h1.x, h1.y, h2.x, h2.y};
            #pragma unroll
            for (int r = 0; r < 8; ++r) {
                dsum[r] += er[r];
                #pragma unroll
                for (int cc = 0; cc < 6; ++cc) acc[r][cc] += er[r] * hr[cc];
            }
        }
        __syncthreads();
    }
    #pragma unroll
    for (int r = 0; r < 8; ++r) {
        int i = i0 + ty * 8 + r;
        float inv = (dsum[r] != 0.f) ? 1.0f / dsum[r] : 0.f;
        float* op = fo_ws + ((size_t)bh * NN + i) * OUT_DIM + tx * 6;
        *(float2*)(op)     = make_float2(acc[r][0] * inv, acc[r][1] * inv);
        *(float2*)(op + 2) = make_float2(acc[r][2] * inv, acc[r][3] * inv);
        *(float2*)(op + 4) = make_float2(acc[r][4] * inv, acc[r][5] * inv);
    }
}

// ---------------- epilogue: bias + elu + sigmoid gate + blend ----------------
__global__ void epilogue_kernel(const float* __restrict__ fo_ws, const float* __restrict__ glog,
                                const float* __restrict__ feat_in, const float* __restrict__ bias,
                                const float* __restrict__ Hb, float* __restrict__ out) {
    int idx = blockIdx.x * 256 + threadIdx.x;   // float4 granularity: 8192*192
    int m = idx / 192, c4 = idx % 192;
    int c = c4 * 4;
    int b = m >> 10, n = m & 1023;
    int hh = c / OUT_DIM, o = c % OUT_DIM;
    float4 fo = *(const float4*)(fo_ws + ((size_t)(b * 8 + hh) * NN + n) * OUT_DIM + o);
    float4 gl = *(const float4*)(glog + (size_t)m * 768 + c);
    float4 x  = *(const float4*)(feat_in + (size_t)m * 768 + c);
    float fv[4] = {fo.x, fo.y, fo.z, fo.w};
    float gv[4] = {gl.x, gl.y, gl.z, gl.w};
    float xv[4] = {x.x, x.y, x.z, x.w};
    float r[4];
    #pragma unroll
    for (int u = 0; u < 4; ++u) {
        float v = fv[u] + bias[o + u];
        float e = (v > 0.f) ? v : (__expf(v) - 1.f);
        float g = 1.f / (1.f + __expf(-(gv[u] + Hb[c + u])));
        r[u] = g * e + (1.f - g) * xv[u];
    }
    *(float4*)(out + (size_t)m * 768 + c) = make_float4(r[0], r[1], r[2], r[3]);
}

extern "C" void kernel_launch(void* const* d_in, const int* in_sizes, int n_in,
                              void* d_out, int out_size, void* d_ws, size_t ws_size,
                              hipStream_t stream) {
    const float* feat_in = (const float*)d_in[0];
    const float* adj     = (const float*)d_in[1];
    const float* W       = (const float*)d_in[2];
    const float* bbias   = (const float*)d_in[3];
    const float* w_src   = (const float*)d_in[4];
    const float* w_dst   = (const float*)d_in[5];
    const float* Hw      = (const float*)d_in[6];
    const float* Hb      = (const float*)d_in[7];
    float* out = (float*)d_out;
    float* ws = (float*)d_ws;

    float* Bcat  = ws + WS_BCAT;
    float* h_ws  = ws + WS_H;
    float* glog  = ws + WS_GLOG;
    float* a_src = ws + WS_ASRC;
    float* a_dst = ws + WS_ADST;
    float* fo_ws = ws + WS_FO;

    pack_w_kernel<<<(IN_DIM * 768 + 255) / 256, 256, 0, stream>>>(W, Bcat);
    pack_hw_kernel<<<dim3(24, 24), 256, 0, stream>>>(Hw, Bcat);
    gemm1_kernel<<<dim3(M_ROWS / 128, NCOLS / 128), 256, 0, stream>>>(feat_in, Bcat, h_ws, glog);
    a_kernel<<<(64 * NN) / 4, 256, 0, stream>>>(h_ws, w_src, w_dst, a_src, a_dst);
    attn_kernel<<<64 * 8, 256, 0, stream>>>(h_ws, adj, a_src, a_dst, fo_ws);
    epilogue_kernel<<<(M_ROWS * 192) / 256, 256, 0, stream>>>(fo_ws, glog, feat_in, bbias, Hb, out);
}

// Round 2
// 291.960 us; speedup vs baseline: 1.9378x; 1.9378x over previous
//
#include <hip/hip_runtime.h>
#include <cstddef>

#define BATCH 8
#define NN 1024
#define IN_DIM 768
#define OUT_DIM 96
#define HEADS 8
#define M_ROWS 8192
#define NCOLS 1536

typedef __attribute__((ext_vector_type(8))) short short8;
typedef __attribute__((ext_vector_type(4))) float f32x4;
typedef __attribute__((ext_vector_type(4))) unsigned short ushort4v;

__device__ __forceinline__ unsigned short f2bf(float x) {
    unsigned int u = __builtin_bit_cast(unsigned int, x);
    u += 0x7fffu + ((u >> 16) & 1u);          // RTNE
    return (unsigned short)(u >> 16);
}
__device__ __forceinline__ float bf2f(unsigned short u) {
    unsigned int v = ((unsigned int)u) << 16;
    return __builtin_bit_cast(float, v);
}
__device__ __forceinline__ float tanh_fast(float x) {
    return 1.f - 2.f / (__expf(2.f * x) + 1.f);
}

// ---------- convert feat_in -> bf16 ----------
__global__ void xb_kernel(const float* __restrict__ x, unsigned short* __restrict__ xb) {
    int idx = blockIdx.x * 256 + threadIdx.x;     // one per 8 elements
    const float4* p = (const float4*)(x + (size_t)idx * 8);
    float4 a = p[0], b = p[1];
    short8 r;
    r[0] = (short)f2bf(a.x); r[1] = (short)f2bf(a.y); r[2] = (short)f2bf(a.z); r[3] = (short)f2bf(a.w);
    r[4] = (short)f2bf(b.x); r[5] = (short)f2bf(b.y); r[6] = (short)f2bf(b.z); r[7] = (short)f2bf(b.w);
    *(short8*)(xb + (size_t)idx * 8) = r;
}

// ---------- pack W and Hw into BcatT[c][k] bf16 (B-transposed: row=c out-col, col=k) ----------
__global__ void pack_w_kernel(const float* __restrict__ W, unsigned short* __restrict__ BT) {
    int idx = blockIdx.x * 256 + threadIdx.x;     // 768*768
    int c = idx / IN_DIM, i = idx % IN_DIM;
    int h = c / OUT_DIM, o = c % OUT_DIM;
    BT[(size_t)c * IN_DIM + i] = f2bf(W[((size_t)h * IN_DIM + i) * OUT_DIM + o]);
}
__global__ void pack_hw_kernel(const float* __restrict__ Hw, unsigned short* __restrict__ BT) {
    int idx = blockIdx.x * 256 + threadIdx.x;     // 768*768
    int c = idx / IN_DIM, i = idx % IN_DIM;
    BT[(size_t)(768 + c) * IN_DIM + i] = f2bf(Hw[(size_t)c * IN_DIM + i]);
}

// ---------- GEMM1: Xb[8192,768] @ BT^T -> h_bt (bf16, [bh][o][n]) + glog (f32) ----------
__global__ __launch_bounds__(256) void gemm1_kernel(
        const unsigned short* __restrict__ Xb, const unsigned short* __restrict__ BT,
        unsigned short* __restrict__ h_bt, float* __restrict__ glog) {
    __shared__ unsigned short As[128 * 72];
    __shared__ unsigned short Bs[128 * 72];
    int m0 = blockIdx.x * 128;
    int c0 = blockIdx.y * 128;
    int t = threadIdx.x;
    int w = t >> 6, lane = t & 63, l15 = t & 15, quad = lane >> 4;
    f32x4 acc[2][8] = {};
    for (int k0 = 0; k0 < IN_DIM; k0 += 64) {
        __syncthreads();
        #pragma unroll
        for (int q = 0; q < 4; ++q) {
            int f = t + q * 256;
            int r = f >> 3, c8 = (f & 7) * 8;
            *(short8*)(As + r * 72 + c8) = *(const short8*)(Xb + (size_t)(m0 + r) * IN_DIM + k0 + c8);
            *(short8*)(Bs + r * 72 + c8) = *(const short8*)(BT + (size_t)(c0 + r) * IN_DIM + k0 + c8);
        }
        __syncthreads();
        #pragma unroll
        for (int ks = 0; ks < 2; ++ks) {
            short8 af[2], bfr[8];
            #pragma unroll
            for (int mt = 0; mt < 2; ++mt)
                af[mt] = *(const short8*)(As + (w * 32 + mt * 16 + l15) * 72 + ks * 32 + quad * 8);
            #pragma unroll
            for (int nt = 0; nt < 8; ++nt)
                bfr[nt] = *(const short8*)(Bs + (nt * 16 + l15) * 72 + ks * 32 + quad * 8);
            #pragma unroll
            for (int mt = 0; mt < 2; ++mt)
                #pragma unroll
                for (int nt = 0; nt < 8; ++nt)
                    acc[mt][nt] = __builtin_amdgcn_mfma_f32_16x16x32_bf16(af[mt], bfr[nt], acc[mt][nt], 0, 0, 0);
        }
    }
    int b = m0 >> 10;
    #pragma unroll
    for (int mt = 0; mt < 2; ++mt) {
        int rowbase = m0 + w * 32 + mt * 16 + quad * 4;
        int nbase = rowbase & 1023;
        #pragma unroll
        for (int nt = 0; nt < 8; ++nt) {
            int c = c0 + nt * 16 + l15;
            if (c < 768) {
                int hh = c / OUT_DIM, o = c % OUT_DIM;
                ushort4v hb;
                hb[0] = f2bf(acc[mt][nt][0]); hb[1] = f2bf(acc[mt][nt][1]);
                hb[2] = f2bf(acc[mt][nt][2]); hb[3] = f2bf(acc[mt][nt][3]);
                *(ushort4v*)(h_bt + ((size_t)(b * 8 + hh) * OUT_DIM + o) * NN + nbase) = hb;
            } else {
                int cg = c - 768;
                #pragma unroll
                for (int reg = 0; reg < 4; ++reg)
                    glog[(size_t)(rowbase + reg) * 768 + cg] = acc[mt][nt][reg];
            }
        }
    }
}

// ---------- a_src/a_dst from bf16 h_bt ----------
__global__ __launch_bounds__(256) void a_kernel(const unsigned short* __restrict__ h_bt,
                                                const float* __restrict__ w_src,
                                                const float* __restrict__ w_dst,
                                                float* __restrict__ a_src, float* __restrict__ a_dst) {
    __shared__ unsigned short ht[96 * 72];
    __shared__ float ws_s[96], wd_s[96];
    __shared__ float pps[4][64], ppd[4][64];
    int bh = blockIdx.x >> 4;
    int n0 = (blockIdx.x & 15) * 64;
    int head = bh & 7;
    int t = threadIdx.x;
    if (t < 96) { ws_s[t] = w_src[head * 96 + t]; wd_s[t] = w_dst[head * 96 + t]; }
    for (int f = t; f < 768; f += 256) {
        int row = f >> 3, c8 = (f & 7) * 8;
        *(short8*)(ht + row * 72 + c8) = *(const short8*)(h_bt + ((size_t)bh * 96 + row) * NN + n0 + c8);
    }
    __syncthreads();
    int n = t & 63, part = t >> 6;
    float ps = 0.f, pd = 0.f;
    #pragma unroll
    for (int oo = 0; oo < 24; ++oo) {
        int o = part * 24 + oo;
        float th = tanh_fast(bf2f(ht[o * 72 + n]));
        ps += th * ws_s[o];
        pd += th * wd_s[o];
    }
    pps[part][n] = ps; ppd[part][n] = pd;
    __syncthreads();
    if (t < 64) {
        float s = pps[0][t] + pps[1][t] + pps[2][t] + pps[3][t];
        float d = ppd[0][t] + ppd[1][t] + ppd[2][t] + ppd[3][t];
        a_src[bh * 1024 + n0 + t] = s;
        a_dst[bh * 1024 + n0 + t] = d;
    }
}

// ---------- attention: MFMA E@h with ones-column row-sum ----------
__global__ __launch_bounds__(256) void attn_kernel(
        const unsigned short* __restrict__ h_bt, const float* __restrict__ adj,
        const float* __restrict__ a_src_g, const float* __restrict__ a_dst_g,
        float* __restrict__ fo_ws) {
    __shared__ unsigned short es[128 * 72];
    __shared__ unsigned short hs[96 * 72];
    __shared__ float adst[1024];
    __shared__ float asrc[128];
    int blk = blockIdx.x;
    int bh = blk >> 3, i0 = (blk & 7) * 128, b = bh >> 3;
    int t = threadIdx.x;
    int w = t >> 6, lane = t & 63, l15 = t & 15, quad = lane >> 4;
    for (int q = 0; q < 4; ++q) adst[q * 256 + t] = a_dst_g[bh * 1024 + q * 256 + t];
    if (t < 128) asrc[t] = a_src_g[bh * 1024 + i0 + t];
    const float* adj_b = adj + (size_t)b * NN * NN;
    const unsigned short* hhp = h_bt + (size_t)bh * 96 * NN;
    f32x4 acc[2][7] = {};
    short8 ones = {};
    if (l15 == 0) {
        #pragma unroll
        for (int u = 0; u < 8; ++u) ones[u] = (short)0x3F80;   // bf16 1.0
    }
    __syncthreads();
    for (int j0 = 0; j0 < 1024; j0 += 64) {
        if (j0) __syncthreads();
        for (int f = t; f < 768; f += 256) {
            int row = f >> 3, c8 = (f & 7) * 8;
            *(short8*)(hs + row * 72 + c8) = *(const short8*)(hhp + (size_t)row * NN + j0 + c8);
        }
        #pragma unroll
        for (int q = 0; q < 8; ++q) {
            int f = t + q * 256;
            int il = f >> 4, j4 = (f & 15) * 4;
            float4 av = *(const float4*)(adj_b + (size_t)(i0 + il) * NN + j0 + j4);
            float si = asrc[il];
            float aa[4] = {av.x, av.y, av.z, av.w};
            ushort4v ev;
            #pragma unroll
            for (int u = 0; u < 4; ++u) {
                float s = si + adst[j0 + j4 + u];
                s = (s >= 0.f) ? s : 0.2f * s;
                float e = (aa[u] != 0.f) ? __expf(s) : 0.f;
                ev[u] = f2bf(e);
            }
            *(ushort4v*)(es + il * 72 + j4) = ev;
        }
        __syncthreads();
        #pragma unroll
        for (int ks = 0; ks < 2; ++ks) {
            short8 af[2];
            #pragma unroll
            for (int mt = 0; mt < 2; ++mt)
                af[mt] = *(const short8*)(es + (w * 32 + mt * 16 + l15) * 72 + ks * 32 + quad * 8);
            #pragma unroll
            for (int nt = 0; nt < 6; ++nt) {
                short8 bfr = *(const short8*)(hs + (nt * 16 + l15) * 72 + ks * 32 + quad * 8);
                acc[0][nt] = __builtin_amdgcn_mfma_f32_16x16x32_bf16(af[0], bfr, acc[0][nt], 0, 0, 0);
                acc[1][nt] = __builtin_amdgcn_mfma_f32_16x16x32_bf16(af[1], bfr, acc[1][nt], 0, 0, 0);
            }
            acc[0][6] = __builtin_amdgcn_mfma_f32_16x16x32_bf16(af[0], ones, acc[0][6], 0, 0, 0);
            acc[1][6] = __builtin_amdgcn_mfma_f32_16x16x32_bf16(af[1], ones, acc[1][6], 0, 0, 0);
        }
    }
    #pragma unroll
    for (int mt = 0; mt < 2; ++mt) {
        int rowq = i0 + w * 32 + mt * 16 + quad * 4;
        #pragma unroll
        for (int reg = 0; reg < 4; ++reg) {
            float s = __shfl(acc[mt][6][reg], (lane & 48));
            float inv = (s > 0.f) ? 1.f / s : 0.f;
            float* op = fo_ws + ((size_t)bh * NN + rowq + reg) * OUT_DIM;
            #pragma unroll
            for (int nt = 0; nt < 6; ++nt)
                op[nt * 16 + l15] = acc[mt][nt][reg] * inv;
        }
    }
}

// ---------- epilogue: bias + elu + sigmoid gate + blend ----------
__global__ void epilogue_kernel(const float* __restrict__ fo_ws, const float* __restrict__ glog,
                                const float* __restrict__ feat_in, const float* __restrict__ bias,
                                const float* __restrict__ Hb, float* __restrict__ out) {
    int idx = blockIdx.x * 256 + threadIdx.x;
    int m = idx / 192, c4 = idx % 192;
    int c = c4 * 4;
    int b = m >> 10, n = m & 1023;
    int hh = c / OUT_DIM, o = c % OUT_DIM;
    float4 fo = *(const float4*)(fo_ws + ((size_t)(b * 8 + hh) * NN + n) * OUT_DIM + o);
    float4 gl = *(const float4*)(glog + (size_t)m * 768 + c);
    float4 x  = *(const float4*)(feat_in + (size_t)m * 768 + c);
    float fv[4] = {fo.x, fo.y, fo.z, fo.w};
    float gv[4] = {gl.x, gl.y, gl.z, gl.w};
    float xv[4] = {x.x, x.y, x.z, x.w};
    float r[4];
    #pragma unroll
    for (int u = 0; u < 4; ++u) {
        float v = fv[u] + bias[o + u];
        float e = (v > 0.f) ? v : (__expf(v) - 1.f);
        float g = 1.f / (1.f + __expf(-(gv[u] + Hb[c + u])));
        r[u] = g * e + (1.f - g) * xv[u];
    }
    *(float4*)(out + (size_t)m * 768 + c) = make_float4(r[0], r[1], r[2], r[3]);
}

extern "C" void kernel_launch(void* const* d_in, const int* in_sizes, int n_in,
                              void* d_out, int out_size, void* d_ws, size_t ws_size,
                              hipStream_t stream) {
    const float* feat_in = (const float*)d_in[0];
    const float* adj     = (const float*)d_in[1];
    const float* W       = (const float*)d_in[2];
    const float* bbias   = (const float*)d_in[3];
    const float* w_src   = (const float*)d_in[4];
    const float* w_dst   = (const float*)d_in[5];
    const float* Hw      = (const float*)d_in[6];
    const float* Hb      = (const float*)d_in[7];
    float* out = (float*)d_out;
    char* base = (char*)d_ws;

    unsigned short* Xb    = (unsigned short*)(base);                 // 12,582,912 B
    unsigned short* BcatT = (unsigned short*)(base + 12582912);      //  2,359,296 B
    unsigned short* h_bt  = (unsigned short*)(base + 14942208);      // 12,582,912 B
    float* glog  = (float*)(base + 27525120);                        // 25,165,824 B
    float* a_src = (float*)(base + 52690944);                        //    262,144 B
    float* a_dst = (float*)(base + 52953088);                        //    262,144 B
    float* fo_ws = (float*)(base + 53215232);                        // 25,165,824 B (end 78.4 MB)

    xb_kernel<<<(M_ROWS * IN_DIM / 8) / 256, 256, 0, stream>>>(feat_in, Xb);
    pack_w_kernel<<<(768 * IN_DIM) / 256, 256, 0, stream>>>(W, BcatT);
    pack_hw_kernel<<<(768 * IN_DIM) / 256, 256, 0, stream>>>(Hw, BcatT);
    gemm1_kernel<<<dim3(M_ROWS / 128, NCOLS / 128), 256, 0, stream>>>(Xb, BcatT, h_bt, glog);
    a_kernel<<<64 * 16, 256, 0, stream>>>(h_bt, w_src, w_dst, a_src, a_dst);
    attn_kernel<<<64 * 8, 256, 0, stream>>>(h_bt, adj, a_src, a_dst, fo_ws);
    epilogue_kernel<<<(M_ROWS * 192) / 256, 256, 0, stream>>>(fo_ws, glog, feat_in, bbias, Hb, out);
}

// Round 3
// 211.184 us; speedup vs baseline: 2.6790x; 1.3825x over previous
//
#include <hip/hip_runtime.h>
#include <cstddef>

#define BATCH 8
#define NN 1024
#define IN_DIM 768
#define OUT_DIM 96
#define HEADS 8
#define M_ROWS 8192
#define NCOLS 1536

typedef __attribute__((ext_vector_type(8))) short short8;
typedef __attribute__((ext_vector_type(4))) float f32x4;
typedef __attribute__((ext_vector_type(4))) unsigned short ushort4v;

__device__ __forceinline__ unsigned short f2bf(float x) {
    unsigned int u = __builtin_bit_cast(unsigned int, x);
    u += 0x7fffu + ((u >> 16) & 1u);          // RTNE
    return (unsigned short)(u >> 16);
}
__device__ __forceinline__ float bf2f(unsigned short u) {
    unsigned int v = ((unsigned int)u) << 16;
    return __builtin_bit_cast(float, v);
}
__device__ __forceinline__ float tanh_fast(float x) {
    return 1.f - 2.f / (__expf(2.f * x) + 1.f);
}

// ---------- convert feat_in -> bf16 ----------
__global__ void xb_kernel(const float* __restrict__ x, unsigned short* __restrict__ xb) {
    int idx = blockIdx.x * 256 + threadIdx.x;
    const float4* p = (const float4*)(x + (size_t)idx * 8);
    float4 a = p[0], b = p[1];
    short8 r;
    r[0] = (short)f2bf(a.x); r[1] = (short)f2bf(a.y); r[2] = (short)f2bf(a.z); r[3] = (short)f2bf(a.w);
    r[4] = (short)f2bf(b.x); r[5] = (short)f2bf(b.y); r[6] = (short)f2bf(b.z); r[7] = (short)f2bf(b.w);
    *(short8*)(xb + (size_t)idx * 8) = r;
}

// ---------- pack W and Hw into BcatT[c][k] bf16 ----------
__global__ void pack_w_kernel(const float* __restrict__ W, unsigned short* __restrict__ BT) {
    int idx = blockIdx.x * 256 + threadIdx.x;
    int c = idx / IN_DIM, i = idx % IN_DIM;
    int h = c / OUT_DIM, o = c % OUT_DIM;
    BT[(size_t)c * IN_DIM + i] = f2bf(W[((size_t)h * IN_DIM + i) * OUT_DIM + o]);
}
__global__ void pack_hw_kernel(const float* __restrict__ Hw, unsigned short* __restrict__ BT) {
    int idx = blockIdx.x * 256 + threadIdx.x;
    int c = idx / IN_DIM, i = idx % IN_DIM;
    BT[(size_t)(768 + c) * IN_DIM + i] = f2bf(Hw[(size_t)c * IN_DIM + i]);
}

// ---------- pack adj -> bitmask (1 bit per edge) ----------
__global__ void pack_abits_kernel(const float* __restrict__ adj, unsigned int* __restrict__ abits) {
    int idx = blockIdx.x * 256 + threadIdx.x;   // 262144 words
    const float4* p = (const float4*)(adj + (size_t)idx * 32);
    unsigned int m = 0;
    #pragma unroll
    for (int q = 0; q < 8; ++q) {
        float4 v = p[q];
        m |= (v.x != 0.f ? 1u : 0u) << (q * 4 + 0);
        m |= (v.y != 0.f ? 1u : 0u) << (q * 4 + 1);
        m |= (v.z != 0.f ? 1u : 0u) << (q * 4 + 2);
        m |= (v.w != 0.f ? 1u : 0u) << (q * 4 + 3);
    }
    abits[idx] = m;
}

// ---------- GEMM1: Xb[8192,768] @ BT^T -> h_bt (bf16, [bh][o][n]) + glog (f32) ----------
__global__ __launch_bounds__(256) void gemm1_kernel(
        const unsigned short* __restrict__ Xb, const unsigned short* __restrict__ BT,
        unsigned short* __restrict__ h_bt, float* __restrict__ glog) {
    __shared__ unsigned short As[128 * 72];
    __shared__ unsigned short Bs[128 * 72];
    int m0 = blockIdx.x * 128;
    int c0 = blockIdx.y * 128;
    int t = threadIdx.x;
    int w = t >> 6, lane = t & 63, l15 = t & 15, quad = lane >> 4;
    f32x4 acc[2][8] = {};
    for (int k0 = 0; k0 < IN_DIM; k0 += 64) {
        __syncthreads();
        #pragma unroll
        for (int q = 0; q < 4; ++q) {
            int f = t + q * 256;
            int r = f >> 3, c8 = (f & 7) * 8;
            *(short8*)(As + r * 72 + c8) = *(const short8*)(Xb + (size_t)(m0 + r) * IN_DIM + k0 + c8);
            *(short8*)(Bs + r * 72 + c8) = *(const short8*)(BT + (size_t)(c0 + r) * IN_DIM + k0 + c8);
        }
        __syncthreads();
        #pragma unroll
        for (int ks = 0; ks < 2; ++ks) {
            short8 af[2], bfr[8];
            #pragma unroll
            for (int mt = 0; mt < 2; ++mt)
                af[mt] = *(const short8*)(As + (w * 32 + mt * 16 + l15) * 72 + ks * 32 + quad * 8);
            #pragma unroll
            for (int nt = 0; nt < 8; ++nt)
                bfr[nt] = *(const short8*)(Bs + (nt * 16 + l15) * 72 + ks * 32 + quad * 8);
            #pragma unroll
            for (int mt = 0; mt < 2; ++mt)
                #pragma unroll
                for (int nt = 0; nt < 8; ++nt)
                    acc[mt][nt] = __builtin_amdgcn_mfma_f32_16x16x32_bf16(af[mt], bfr[nt], acc[mt][nt], 0, 0, 0);
        }
    }
    int b = m0 >> 10;
    #pragma unroll
    for (int mt = 0; mt < 2; ++mt) {
        int rowbase = m0 + w * 32 + mt * 16 + quad * 4;
        int nbase = rowbase & 1023;
        #pragma unroll
        for (int nt = 0; nt < 8; ++nt) {
            int c = c0 + nt * 16 + l15;
            if (c < 768) {
                int hh = c / OUT_DIM, o = c % OUT_DIM;
                ushort4v hb;
                hb[0] = f2bf(acc[mt][nt][0]); hb[1] = f2bf(acc[mt][nt][1]);
                hb[2] = f2bf(acc[mt][nt][2]); hb[3] = f2bf(acc[mt][nt][3]);
                *(ushort4v*)(h_bt + ((size_t)(b * 8 + hh) * OUT_DIM + o) * NN + nbase) = hb;
            } else {
                int cg = c - 768;
                #pragma unroll
                for (int reg = 0; reg < 4; ++reg)
                    glog[(size_t)(rowbase + reg) * 768 + cg] = acc[mt][nt][reg];
            }
        }
    }
}

// ---------- a_src/a_dst from bf16 h_bt (pre-scaled by log2(e)) ----------
__global__ __launch_bounds__(256) void a_kernel(const unsigned short* __restrict__ h_bt,
                                                const float* __restrict__ w_src,
                                                const float* __restrict__ w_dst,
                                                float* __restrict__ a_src, float* __restrict__ a_dst) {
    __shared__ unsigned short ht[96 * 72];
    __shared__ float ws_s[96], wd_s[96];
    __shared__ float pps[4][64], ppd[4][64];
    int bh = blockIdx.x >> 4;
    int n0 = (blockIdx.x & 15) * 64;
    int head = bh & 7;
    int t = threadIdx.x;
    if (t < 96) { ws_s[t] = w_src[head * 96 + t]; wd_s[t] = w_dst[head * 96 + t]; }
    for (int f = t; f < 768; f += 256) {
        int row = f >> 3, c8 = (f & 7) * 8;
        *(short8*)(ht + row * 72 + c8) = *(const short8*)(h_bt + ((size_t)bh * 96 + row) * NN + n0 + c8);
    }
    __syncthreads();
    int n = t & 63, part = t >> 6;
    float ps = 0.f, pd = 0.f;
    #pragma unroll
    for (int oo = 0; oo < 24; ++oo) {
        int o = part * 24 + oo;
        float th = tanh_fast(bf2f(ht[o * 72 + n]));
        ps += th * ws_s[o];
        pd += th * wd_s[o];
    }
    pps[part][n] = ps; ppd[part][n] = pd;
    __syncthreads();
    if (t < 64) {
        float s = pps[0][t] + pps[1][t] + pps[2][t] + pps[3][t];
        float d = ppd[0][t] + ppd[1][t] + ppd[2][t] + ppd[3][t];
        a_src[bh * 1024 + n0 + t] = s * 1.44269504f;    // log2(e) folded for exp2
        a_dst[bh * 1024 + n0 + t] = d * 1.44269504f;
    }
}

// ---------- attention: i-tile 64, bitmask adj, register double-buffer, MFMA E@h ----------
__global__ __launch_bounds__(256) void attn_kernel(
        const unsigned short* __restrict__ h_bt, const unsigned int* __restrict__ abits,
        const float* __restrict__ a_src_g, const float* __restrict__ a_dst_g,
        float* __restrict__ fo_ws) {
    __shared__ __align__(16) unsigned short es[64 * 72];
    __shared__ __align__(16) unsigned short hs[96 * 72];
    __shared__ __align__(16) float adst[1024];
    __shared__ __align__(16) float asrc[64];
    int blk = blockIdx.x;
    int bh = blk >> 4, i0 = (blk & 15) * 64, b = bh >> 3;
    int t = threadIdx.x;
    int w = t >> 6, lane = t & 63, l15 = t & 15, quad = lane >> 4;
    for (int q = 0; q < 4; ++q) adst[q * 256 + t] = a_dst_g[bh * 1024 + q * 256 + t];
    if (t < 64) asrc[t] = a_src_g[bh * 1024 + i0 + t];
    const unsigned short* hhp = h_bt + (size_t)bh * 96 * NN;
    int il = t >> 2, jq = (t & 3) * 16;
    const unsigned int* ab_row = abits + ((size_t)b * NN + i0 + il) * 32;
    // prefetch iter 0
    short8 hreg[3];
    #pragma unroll
    for (int q = 0; q < 3; ++q) {
        int f = t + q * 256;
        int row = f >> 3, c8 = (f & 7) * 8;
        hreg[q] = *(const short8*)(hhp + (size_t)row * NN + c8);
    }
    unsigned int mword = ab_row[jq >> 5];
    f32x4 acc[7] = {};
    short8 ones = {};
    if (l15 == 0) {
        #pragma unroll
        for (int u = 0; u < 8; ++u) ones[u] = (short)0x3F80;
    }
    __syncthreads();
    float si = asrc[il];
    for (int j0 = 0; j0 < 1024; j0 += 64) {
        // stage h tile from prefetched regs
        #pragma unroll
        for (int q = 0; q < 3; ++q) {
            int f = t + q * 256;
            int row = f >> 3, c8 = (f & 7) * 8;
            *(short8*)(hs + row * 72 + c8) = hreg[q];
        }
        // E build: 16 values per thread from one mask dword half
        unsigned int m16 = (mword >> (jq & 16)) & 0xFFFFu;
        f32x4 dv[4];
        #pragma unroll
        for (int q = 0; q < 4; ++q) dv[q] = *(const f32x4*)(&adst[j0 + jq + q * 4]);
        float ev[16];
        #pragma unroll
        for (int u = 0; u < 16; ++u) {
            float s = si + dv[u >> 2][u & 3];
            float l = fmaxf(s, 0.2f * s);
            float e = __builtin_amdgcn_exp2f(l);
            ev[u] = ((m16 >> u) & 1u) ? e : 0.f;
        }
        union { unsigned int u[8]; short8 s8[2]; } pk;
        #pragma unroll
        for (int p = 0; p < 8; ++p) {
            unsigned int u0 = __builtin_bit_cast(unsigned int, ev[2 * p]) + 0x8000u;
            unsigned int u1 = __builtin_bit_cast(unsigned int, ev[2 * p + 1]) + 0x8000u;
            pk.u[p] = __builtin_amdgcn_perm(u1, u0, 0x07060302);
        }
        *(short8*)(es + il * 72 + jq) = pk.s8[0];
        *(short8*)(es + il * 72 + jq + 8) = pk.s8[1];
        // prefetch next iter (flies across the MFMA phase)
        int jn = j0 + 64;
        if (jn < 1024) {
            #pragma unroll
            for (int q = 0; q < 3; ++q) {
                int f = t + q * 256;
                int row = f >> 3, c8 = (f & 7) * 8;
                hreg[q] = *(const short8*)(hhp + (size_t)row * NN + jn + c8);
            }
            mword = ab_row[(jn + jq) >> 5];
        }
        __syncthreads();
        #pragma unroll
        for (int ks = 0; ks < 2; ++ks) {
            short8 af = *(const short8*)(es + (w * 16 + l15) * 72 + ks * 32 + quad * 8);
            #pragma unroll
            for (int nt = 0; nt < 6; ++nt) {
                short8 bfr = *(const short8*)(hs + (nt * 16 + l15) * 72 + ks * 32 + quad * 8);
                acc[nt] = __builtin_amdgcn_mfma_f32_16x16x32_bf16(af, bfr, acc[nt], 0, 0, 0);
            }
            acc[6] = __builtin_amdgcn_mfma_f32_16x16x32_bf16(af, ones, acc[6], 0, 0, 0);
        }
        __syncthreads();
    }
    int rowq = i0 + w * 16 + quad * 4;
    #pragma unroll
    for (int reg = 0; reg < 4; ++reg) {
        float ssum = __shfl(acc[6][reg], (lane & 48));   // ones-column sum lives at l15==0
        float inv = (ssum > 0.f) ? 1.f / ssum : 0.f;
        float* op = fo_ws + ((size_t)bh * NN + rowq + reg) * OUT_DIM;
        #pragma unroll
        for (int nt = 0; nt < 6; ++nt)
            op[nt * 16 + l15] = acc[nt][reg] * inv;
    }
}

// ---------- epilogue: bias + elu + sigmoid gate + blend ----------
__global__ void epilogue_kernel(const float* __restrict__ fo_ws, const float* __restrict__ glog,
                                const float* __restrict__ feat_in, const float* __restrict__ bias,
                                const float* __restrict__ Hb, float* __restrict__ out) {
    int idx = blockIdx.x * 256 + threadIdx.x;
    int m = idx / 192, c4 = idx % 192;
    int c = c4 * 4;
    int b = m >> 10, n = m & 1023;
    int hh = c / OUT_DIM, o = c % OUT_DIM;
    float4 fo = *(const float4*)(fo_ws + ((size_t)(b * 8 + hh) * NN + n) * OUT_DIM + o);
    float4 gl = *(const float4*)(glog + (size_t)m * 768 + c);
    float4 x  = *(const float4*)(feat_in + (size_t)m * 768 + c);
    float fv[4] = {fo.x, fo.y, fo.z, fo.w};
    float gv[4] = {gl.x, gl.y, gl.z, gl.w};
    float xv[4] = {x.x, x.y, x.z, x.w};
    float r[4];
    #pragma unroll
    for (int u = 0; u < 4; ++u) {
        float v = fv[u] + bias[o + u];
        float e = (v > 0.f) ? v : (__expf(v) - 1.f);
        float g = 1.f / (1.f + __expf(-(gv[u] + Hb[c + u])));
        r[u] = g * e + (1.f - g) * xv[u];
    }
    *(float4*)(out + (size_t)m * 768 + c) = make_float4(r[0], r[1], r[2], r[3]);
}

extern "C" void kernel_launch(void* const* d_in, const int* in_sizes, int n_in,
                              void* d_out, int out_size, void* d_ws, size_t ws_size,
                              hipStream_t stream) {
    const float* feat_in = (const float*)d_in[0];
    const float* adj     = (const float*)d_in[1];
    const float* W       = (const float*)d_in[2];
    const float* bbias   = (const float*)d_in[3];
    const float* w_src   = (const float*)d_in[4];
    const float* w_dst   = (const float*)d_in[5];
    const float* Hw      = (const float*)d_in[6];
    const float* Hb      = (const float*)d_in[7];
    float* out = (float*)d_out;
    char* base = (char*)d_ws;

    unsigned short* Xb    = (unsigned short*)(base);                 // 12,582,912 B (dead after gemm1)
    unsigned short* BcatT = (unsigned short*)(base + 12582912);      //  2,359,296 B
    unsigned short* h_bt  = (unsigned short*)(base + 14942208);      // 12,582,912 B
    float* glog  = (float*)(base + 27525120);                        // 25,165,824 B
    float* a_src = (float*)(base + 52690944);
    float* a_dst = (float*)(base + 52953088);
    float* fo_ws = (float*)(base + 53215232);                        // 25,165,824 B (end 78.4 MB)
    unsigned int* abits = (unsigned int*)(base);                     // overlays Xb (1 MB), written post-gemm1

    xb_kernel<<<(M_ROWS * IN_DIM / 8) / 256, 256, 0, stream>>>(feat_in, Xb);
    pack_w_kernel<<<(768 * IN_DIM) / 256, 256, 0, stream>>>(W, BcatT);
    pack_hw_kernel<<<(768 * IN_DIM) / 256, 256, 0, stream>>>(Hw, BcatT);
    gemm1_kernel<<<dim3(M_ROWS / 128, NCOLS / 128), 256, 0, stream>>>(Xb, BcatT, h_bt, glog);
    pack_abits_kernel<<<(BATCH * NN * NN / 32) / 256, 256, 0, stream>>>(adj, abits);
    a_kernel<<<64 * 16, 256, 0, stream>>>(h_bt, w_src, w_dst, a_src, a_dst);
    attn_kernel<<<64 * 16, 256, 0, stream>>>(h_bt, abits, a_src, a_dst, fo_ws);
    epilogue_kernel<<<(M_ROWS * 192) / 256, 256, 0, stream>>>(fo_ws, glog, feat_in, bbias, Hb, out);
}

// Round 4
// 195.924 us; speedup vs baseline: 2.8877x; 1.0779x over previous
//
#include <hip/hip_runtime.h>
#include <cstddef>

#define BATCH 8
#define NN 1024
#define IN_DIM 768
#define OUT_DIM 96
#define HEADS 8
#define M_ROWS 8192
#define NCOLS 1536

typedef __attribute__((ext_vector_type(8))) short short8;
typedef __attribute__((ext_vector_type(4))) float f32x4;
typedef __attribute__((ext_vector_type(4))) unsigned short ushort4v;

typedef __attribute__((address_space(1))) void gvoid_t;
typedef __attribute__((address_space(3))) void lvoid_t;

// async global->LDS, 16B per lane; lds dest = wave-uniform base + lane*16
__device__ __forceinline__ void gload_lds16(const void* g, void* l) {
    __builtin_amdgcn_global_load_lds((gvoid_t*)(unsigned long long)g,
                                     (lvoid_t*)(unsigned int)(unsigned long long)l,
                                     16, 0, 0);
}

__device__ __forceinline__ unsigned short f2bf(float x) {
    unsigned int u = __builtin_bit_cast(unsigned int, x);
    u += 0x7fffu + ((u >> 16) & 1u);          // RTNE
    return (unsigned short)(u >> 16);
}
__device__ __forceinline__ float bf2f(unsigned short u) {
    unsigned int v = ((unsigned int)u) << 16;
    return __builtin_bit_cast(float, v);
}
__device__ __forceinline__ float tanh_fast(float x) {
    return 1.f - 2.f / (__expf(2.f * x) + 1.f);
}

// ---------- convert feat_in -> bf16 ----------
__global__ void xb_kernel(const float* __restrict__ x, unsigned short* __restrict__ xb) {
    int idx = blockIdx.x * 256 + threadIdx.x;
    const float4* p = (const float4*)(x + (size_t)idx * 8);
    float4 a = p[0], b = p[1];
    short8 r;
    r[0] = (short)f2bf(a.x); r[1] = (short)f2bf(a.y); r[2] = (short)f2bf(a.z); r[3] = (short)f2bf(a.w);
    r[4] = (short)f2bf(b.x); r[5] = (short)f2bf(b.y); r[6] = (short)f2bf(b.z); r[7] = (short)f2bf(b.w);
    *(short8*)(xb + (size_t)idx * 8) = r;
}

// ---------- pack W and Hw into BcatT[c][k] bf16 ----------
__global__ void pack_w_kernel(const float* __restrict__ W, unsigned short* __restrict__ BT) {
    int idx = blockIdx.x * 256 + threadIdx.x;
    int c = idx / IN_DIM, i = idx % IN_DIM;
    int h = c / OUT_DIM, o = c % OUT_DIM;
    BT[(size_t)c * IN_DIM + i] = f2bf(W[((size_t)h * IN_DIM + i) * OUT_DIM + o]);
}
__global__ void pack_hw_kernel(const float* __restrict__ Hw, unsigned short* __restrict__ BT) {
    int idx = blockIdx.x * 256 + threadIdx.x;
    int c = idx / IN_DIM, i = idx % IN_DIM;
    BT[(size_t)(768 + c) * IN_DIM + i] = f2bf(Hw[(size_t)c * IN_DIM + i]);
}

// ---------- pack adj -> bitmask ----------
__global__ void pack_abits_kernel(const float* __restrict__ adj, unsigned int* __restrict__ abits) {
    int idx = blockIdx.x * 256 + threadIdx.x;   // 262144 words
    const float4* p = (const float4*)(adj + (size_t)idx * 32);
    unsigned int m = 0;
    #pragma unroll
    for (int q = 0; q < 8; ++q) {
        float4 v = p[q];
        m |= (v.x != 0.f ? 1u : 0u) << (q * 4 + 0);
        m |= (v.y != 0.f ? 1u : 0u) << (q * 4 + 1);
        m |= (v.z != 0.f ? 1u : 0u) << (q * 4 + 2);
        m |= (v.w != 0.f ? 1u : 0u) << (q * 4 + 3);
    }
    abits[idx] = m;
}

// ---------- GEMM1: Xb[8192,768] @ BT^T -> h_bt (bf16 [bh][o][n]) + glog (f32) ----------
// global_load_lds staging, XOR-swizzled LDS (chunk qb ^ (row&7)), 128x128 tile, BK=64.
__global__ __launch_bounds__(256) void gemm1_kernel(
        const unsigned short* __restrict__ Xb, const unsigned short* __restrict__ BT,
        unsigned short* __restrict__ h_bt, float* __restrict__ glog) {
    __shared__ __align__(16) unsigned short As[128 * 64];
    __shared__ __align__(16) unsigned short Bs[128 * 64];
    int m0 = blockIdx.x * 128;
    int c0 = blockIdx.y * 128;
    int t = threadIdx.x;
    int w = t >> 6, lane = t & 63, l15 = t & 15, quad = lane >> 4;
    f32x4 acc[2][8] = {};
    for (int k0 = 0; k0 < IN_DIM; k0 += 64) {
        __syncthreads();
        #pragma unroll
        for (int cc = 0; cc < 4; ++cc) {
            int base64 = (w * 4 + cc) * 64;          // wave-uniform chunk base
            int p = base64 + lane;
            int r = p >> 3, qs = p & 7;
            int qb = qs ^ (r & 7);                   // inverse of read-side swizzle
            gload_lds16(Xb + (size_t)(m0 + r) * IN_DIM + k0 + qb * 8, As + base64 * 8);
            gload_lds16(BT + (size_t)(c0 + r) * IN_DIM + k0 + qb * 8, Bs + base64 * 8);
        }
        __syncthreads();
        #pragma unroll
        for (int ks = 0; ks < 2; ++ks) {
            short8 af[2], bfr[8];
            #pragma unroll
            for (int mt = 0; mt < 2; ++mt) {
                int r = w * 32 + mt * 16 + l15;
                int cb = (ks * 4 + quad) ^ (r & 7);
                af[mt] = *(const short8*)(As + r * 64 + cb * 8);
            }
            #pragma unroll
            for (int nt = 0; nt < 8; ++nt) {
                int r = nt * 16 + l15;
                int cb = (ks * 4 + quad) ^ (r & 7);
                bfr[nt] = *(const short8*)(Bs + r * 64 + cb * 8);
            }
            #pragma unroll
            for (int mt = 0; mt < 2; ++mt)
                #pragma unroll
                for (int nt = 0; nt < 8; ++nt)
                    acc[mt][nt] = __builtin_amdgcn_mfma_f32_16x16x32_bf16(af[mt], bfr[nt], acc[mt][nt], 0, 0, 0);
        }
    }
    int b = m0 >> 10;
    #pragma unroll
    for (int mt = 0; mt < 2; ++mt) {
        int rowbase = m0 + w * 32 + mt * 16 + quad * 4;
        int nbase = rowbase & 1023;
        #pragma unroll
        for (int nt = 0; nt < 8; ++nt) {
            int c = c0 + nt * 16 + l15;
            if (c < 768) {
                int hh = c / OUT_DIM, o = c % OUT_DIM;
                ushort4v hb;
                hb[0] = f2bf(acc[mt][nt][0]); hb[1] = f2bf(acc[mt][nt][1]);
                hb[2] = f2bf(acc[mt][nt][2]); hb[3] = f2bf(acc[mt][nt][3]);
                *(ushort4v*)(h_bt + ((size_t)(b * 8 + hh) * OUT_DIM + o) * NN + nbase) = hb;
            } else {
                int cg = c - 768;
                #pragma unroll
                for (int reg = 0; reg < 4; ++reg)
                    glog[(size_t)(rowbase + reg) * 768 + cg] = acc[mt][nt][reg];
            }
        }
    }
}

// ---------- a_src/a_dst from bf16 h_bt (pre-scaled by log2(e)) ----------
__global__ __launch_bounds__(256) void a_kernel(const unsigned short* __restrict__ h_bt,
                                                const float* __restrict__ w_src,
                                                const float* __restrict__ w_dst,
                                                float* __restrict__ a_src, float* __restrict__ a_dst) {
    __shared__ unsigned short ht[96 * 72];
    __shared__ float ws_s[96], wd_s[96];
    __shared__ float pps[4][64], ppd[4][64];
    int bh = blockIdx.x >> 4;
    int n0 = (blockIdx.x & 15) * 64;
    int head = bh & 7;
    int t = threadIdx.x;
    if (t < 96) { ws_s[t] = w_src[head * 96 + t]; wd_s[t] = w_dst[head * 96 + t]; }
    for (int f = t; f < 768; f += 256) {
        int row = f >> 3, c8 = (f & 7) * 8;
        *(short8*)(ht + row * 72 + c8) = *(const short8*)(h_bt + ((size_t)bh * 96 + row) * NN + n0 + c8);
    }
    __syncthreads();
    int n = t & 63, part = t >> 6;
    float ps = 0.f, pd = 0.f;
    #pragma unroll
    for (int oo = 0; oo < 24; ++oo) {
        int o = part * 24 + oo;
        float th = tanh_fast(bf2f(ht[o * 72 + n]));
        ps += th * ws_s[o];
        pd += th * wd_s[o];
    }
    pps[part][n] = ps; ppd[part][n] = pd;
    __syncthreads();
    if (t < 64) {
        float s = pps[0][t] + pps[1][t] + pps[2][t] + pps[3][t];
        float d = ppd[0][t] + ppd[1][t] + ppd[2][t] + ppd[3][t];
        a_src[bh * 1024 + n0 + t] = s * 1.44269504f;    // log2(e) folded for exp2
        a_dst[bh * 1024 + n0 + t] = d * 1.44269504f;
    }
}

// ---------- attention + fused epilogue ----------
__global__ __launch_bounds__(256) void attn_kernel(
        const unsigned short* __restrict__ h_bt, const unsigned int* __restrict__ abits,
        const float* __restrict__ a_src_g, const float* __restrict__ a_dst_g,
        const float* __restrict__ glog, const float* __restrict__ feat_in,
        const float* __restrict__ bias, const float* __restrict__ Hb,
        float* __restrict__ out) {
    __shared__ __align__(16) unsigned short es[64 * 72];
    __shared__ __align__(16) unsigned short hs[96 * 72];
    __shared__ __align__(16) float adst[1024];
    __shared__ __align__(16) float asrc[64];
    __shared__ float bias_s[96], hb_s[96];
    int blk = blockIdx.x;
    int bh = blk >> 4, i0 = (blk & 15) * 64, b = bh >> 3, hh = bh & 7;
    int t = threadIdx.x;
    int w = t >> 6, lane = t & 63, l15 = t & 15, quad = lane >> 4;
    for (int q = 0; q < 4; ++q) adst[q * 256 + t] = a_dst_g[bh * 1024 + q * 256 + t];
    if (t < 64) asrc[t] = a_src_g[bh * 1024 + i0 + t];
    if (t >= 64 && t < 160) { bias_s[t - 64] = bias[t - 64]; hb_s[t - 64] = Hb[hh * 96 + t - 64]; }
    const unsigned short* hhp = h_bt + (size_t)bh * 96 * NN;
    int il = t >> 2, jq = (t & 3) * 16;
    const unsigned int* ab_row = abits + ((size_t)b * NN + i0 + il) * 32;
    // prefetch iter 0
    short8 hreg[3];
    #pragma unroll
    for (int q = 0; q < 3; ++q) {
        int f = t + q * 256;
        int row = f >> 3, c8 = (f & 7) * 8;
        hreg[q] = *(const short8*)(hhp + (size_t)row * NN + c8);
    }
    unsigned int mword = ab_row[jq >> 5];
    f32x4 acc[7] = {};
    short8 ones = {};
    if (l15 == 0) {
        #pragma unroll
        for (int u = 0; u < 8; ++u) ones[u] = (short)0x3F80;
    }
    __syncthreads();
    float si = asrc[il];
    for (int j0 = 0; j0 < 1024; j0 += 64) {
        #pragma unroll
        for (int q = 0; q < 3; ++q) {
            int f = t + q * 256;
            int row = f >> 3, c8 = (f & 7) * 8;
            *(short8*)(hs + row * 72 + c8) = hreg[q];
        }
        unsigned int m16 = (mword >> (jq & 16)) & 0xFFFFu;
        f32x4 dv[4];
        #pragma unroll
        for (int q = 0; q < 4; ++q) dv[q] = *(const f32x4*)(&adst[j0 + jq + q * 4]);
        float ev[16];
        #pragma unroll
        for (int u = 0; u < 16; ++u) {
            float s = si + dv[u >> 2][u & 3];
            float l = fmaxf(s, 0.2f * s);
            float e = __builtin_amdgcn_exp2f(l);
            ev[u] = ((m16 >> u) & 1u) ? e : 0.f;
        }
        union { unsigned int u[8]; short8 s8[2]; } pk;
        #pragma unroll
        for (int p = 0; p < 8; ++p) {
            unsigned int u0 = __builtin_bit_cast(unsigned int, ev[2 * p]) + 0x8000u;
            unsigned int u1 = __builtin_bit_cast(unsigned int, ev[2 * p + 1]) + 0x8000u;
            pk.u[p] = __builtin_amdgcn_perm(u1, u0, 0x07060302);
        }
        *(short8*)(es + il * 72 + jq) = pk.s8[0];
        *(short8*)(es + il * 72 + jq + 8) = pk.s8[1];
        int jn = j0 + 64;
        if (jn < 1024) {
            #pragma unroll
            for (int q = 0; q < 3; ++q) {
                int f = t + q * 256;
                int row = f >> 3, c8 = (f & 7) * 8;
                hreg[q] = *(const short8*)(hhp + (size_t)row * NN + jn + c8);
            }
            mword = ab_row[(jn + jq) >> 5];
        }
        __syncthreads();
        #pragma unroll
        for (int ks = 0; ks < 2; ++ks) {
            short8 af = *(const short8*)(es + (w * 16 + l15) * 72 + ks * 32 + quad * 8);
            #pragma unroll
            for (int nt = 0; nt < 6; ++nt) {
                short8 bfr = *(const short8*)(hs + (nt * 16 + l15) * 72 + ks * 32 + quad * 8);
                acc[nt] = __builtin_amdgcn_mfma_f32_16x16x32_bf16(af, bfr, acc[nt], 0, 0, 0);
            }
            acc[6] = __builtin_amdgcn_mfma_f32_16x16x32_bf16(af, ones, acc[6], 0, 0, 0);
        }
        __syncthreads();
    }
    // fused epilogue: bias + elu + sigmoid(glog+Hb) gate + blend -> out
    int rowq = i0 + w * 16 + quad * 4;
    #pragma unroll
    for (int reg = 0; reg < 4; ++reg) {
        float ssum = __shfl(acc[6][reg], (lane & 48));
        float inv = (ssum > 0.f) ? 1.f / ssum : 0.f;
        int n = rowq + reg;
        size_t mrow = ((size_t)b * NN + n) * 768 + hh * 96;
        #pragma unroll
        for (int nt = 0; nt < 6; ++nt) {
            int cl = nt * 16 + l15;
            float fo = acc[nt][reg] * inv + bias_s[cl];
            float e = (fo > 0.f) ? fo : (__expf(fo) - 1.f);
            float z = glog[mrow + cl] + hb_s[cl];
            float g = 1.f / (1.f + __expf(-z));
            float x = feat_in[mrow + cl];
            out[mrow + cl] = g * e + (1.f - g) * x;
        }
    }
}

extern "C" void kernel_launch(void* const* d_in, const int* in_sizes, int n_in,
                              void* d_out, int out_size, void* d_ws, size_t ws_size,
                              hipStream_t stream) {
    const float* feat_in = (const float*)d_in[0];
    const float* adj     = (const float*)d_in[1];
    const float* W       = (const float*)d_in[2];
    const float* bbias   = (const float*)d_in[3];
    const float* w_src   = (const float*)d_in[4];
    const float* w_dst   = (const float*)d_in[5];
    const float* Hw      = (const float*)d_in[6];
    const float* Hb      = (const float*)d_in[7];
    float* out = (float*)d_out;
    char* base = (char*)d_ws;

    unsigned short* Xb    = (unsigned short*)(base);                 // 12,582,912 B (dead after gemm1)
    unsigned short* BcatT = (unsigned short*)(base + 12582912);      //  2,359,296 B
    unsigned short* h_bt  = (unsigned short*)(base + 14942208);      // 12,582,912 B
    float* glog  = (float*)(base + 27525120);                        // 25,165,824 B
    float* a_src = (float*)(base + 52690944);
    float* a_dst = (float*)(base + 52953088);                        // end ~53.2 MB
    unsigned int* abits = (unsigned int*)(base);                     // overlays Xb, written post-gemm1

    xb_kernel<<<(M_ROWS * IN_DIM / 8) / 256, 256, 0, stream>>>(feat_in, Xb);
    pack_w_kernel<<<(768 * IN_DIM) / 256, 256, 0, stream>>>(W, BcatT);
    pack_hw_kernel<<<(768 * IN_DIM) / 256, 256, 0, stream>>>(Hw, BcatT);
    gemm1_kernel<<<dim3(M_ROWS / 128, NCOLS / 128), 256, 0, stream>>>(Xb, BcatT, h_bt, glog);
    pack_abits_kernel<<<(BATCH * NN * NN / 32) / 256, 256, 0, stream>>>(adj, abits);
    a_kernel<<<64 * 16, 256, 0, stream>>>(h_bt, w_src, w_dst, a_src, a_dst);
    attn_kernel<<<64 * 16, 256, 0, stream>>>(h_bt, abits, a_src, a_dst, glog, feat_in, bbias, Hb, out);
}